// Round 11
// baseline (402.453 us; speedup 1.0000x reference)
//
#include <hip/hip_runtime.h>
#include <math.h>

// Problem constants
#define NROWS 16384   // 32*512
#define H     768
#define KEXP  6912    // 768 (silu*base_w) + 768*8 (bases*spline_w*scaler)
#define NCHUNK 108    // KEXP/64
#define K2_BLK 64     // rows per kan2 block

typedef __attribute__((ext_vector_type(8))) short  bhalf8;
typedef __attribute__((ext_vector_type(4))) float  floatx4;

__device__ __forceinline__ unsigned short f2bf(float f) {
    unsigned int u = __float_as_uint(f);
    u = (u + 0x7FFFu + ((u >> 16) & 1u)) >> 16;   // RNE
    return (unsigned short)u;
}
__device__ __forceinline__ float bf2f(unsigned short h) {
    return __uint_as_float(((unsigned int)h) << 16);
}
__device__ __forceinline__ unsigned int pack2(unsigned short a, unsigned short b) {
    return (unsigned int)a | ((unsigned int)b << 16);
}
__device__ __forceinline__ float silu_f(float x) { return x / (1.0f + __expf(-x)); }

// Branch-free tanh-form GELU (R10-verified: absmax unchanged at 0.125)
__device__ __forceinline__ float gelu_fast(float x) {
    float x3 = x * x * x;
    float y = fmaf(x3, 0.0356774081f, x * 0.7978845608f);
    float e = __expf(2.0f * y);
    float th = 1.0f - 2.0f / (e + 1.0f);
    return 0.5f * x * (1.0f + th);
}

// Closed-form cubic B-spline bases on uniform knots g[j] = (j-3)*0.4 - 1.
// (round-4-verified: identical absmax to Cox-de-Boor recursion)
__device__ __forceinline__ void kan_bases(float x, float* __restrict__ b) {
    const float c6 = 0.166666666667f;
    float u  = fmaf(x, 2.5f, 5.5f);      // (x + 2.2) / 0.4
    float fj = floorf(u);
    float t  = u - fj;                    // in [0,1)
    int  j0  = (int)fj;
    float t2 = t * t, t3 = t2 * t;
    float n0 = t3 * c6;
    float n1 = fmaf(t3, -0.5f, fmaf(t2, 0.5f, fmaf(t, 0.5f, c6)));
    float n2 = fmaf(t3, 0.5f, fmaf(t2, -1.0f, 0.666666666667f));
    float omt = 1.0f - t;
    float n3 = omt * omt * omt * c6;
#pragma unroll
    for (int c = 0; c < 8; ++c) {
        int d = j0 - c;
        float v = (d == 0) ? n0 : 0.0f;
        v = (d == 1) ? n1 : v;
        v = (d == 2) ? n2 : v;
        v = (d == 3) ? n3 : v;
        b[c] = v;
    }
}

// ---- Merged prep: W' bf16 [768][6912] (blocks 0..767) and
//      F bf16 [16384][6912] (blocks 768..17151). (byte-identical to R10)
__global__ __launch_bounds__(256) void prep_expand(
    const float* __restrict__ x, const float* __restrict__ bw,
    const float* __restrict__ sw, const float* __restrict__ sc,
    unsigned short* __restrict__ wp, unsigned short* __restrict__ F)
{
    const int b = blockIdx.x, t = threadIdx.x;
    if (b < H) {
        const int n = b;
        const float* bwr = bw + (size_t)n * H;
        unsigned short* out = wp + (size_t)n * KEXP;
        if (t < 96) {
            const float4* xp = (const float4*)(bwr + t * 8);
            float4 v0 = xp[0], v1 = xp[1];
            uint4 pk;
            pk.x = pack2(f2bf(v0.x), f2bf(v0.y));
            pk.y = pack2(f2bf(v0.z), f2bf(v0.w));
            pk.z = pack2(f2bf(v1.x), f2bf(v1.y));
            pk.w = pack2(f2bf(v1.z), f2bf(v1.w));
            *(uint4*)(out + t * 8) = pk;
        }
#pragma unroll
        for (int p = 0; p < 3; ++p) {
            int i = t + p * 256;
            float s = sc[(size_t)n * H + i];
            const float4* swp = (const float4*)(sw + ((size_t)n * H + i) * 8);
            float4 w0 = swp[0], w1 = swp[1];
            uint4 pk;
            pk.x = pack2(f2bf(w0.x * s), f2bf(w0.y * s));
            pk.y = pack2(f2bf(w0.z * s), f2bf(w0.w * s));
            pk.z = pack2(f2bf(w1.x * s), f2bf(w1.y * s));
            pk.w = pack2(f2bf(w1.z * s), f2bf(w1.w * s));
            *(uint4*)(out + H + (size_t)i * 8) = pk;
        }
    } else {
        const int n = b - H;
        __shared__ float sX[H];
        const float* xr = x + (size_t)n * H;
        if (t < 192) ((float4*)sX)[t] = ((const float4*)xr)[t];
        __syncthreads();
        unsigned short* out = F + (size_t)n * KEXP;
        if (t < 96) {
            const float4* xp = (const float4*)(sX + t * 8);
            float4 v0 = xp[0], v1 = xp[1];
            uint4 pk;
            pk.x = pack2(f2bf(silu_f(v0.x)), f2bf(silu_f(v0.y)));
            pk.y = pack2(f2bf(silu_f(v0.z)), f2bf(silu_f(v0.w)));
            pk.z = pack2(f2bf(silu_f(v1.x)), f2bf(silu_f(v1.y)));
            pk.w = pack2(f2bf(silu_f(v1.z)), f2bf(silu_f(v1.w)));
            *(uint4*)(out + t * 8) = pk;
        }
#pragma unroll
        for (int p = 0; p < 3; ++p) {
            int i = t + p * 256;
            float xv = sX[i];
            float bb[8];
            kan_bases(xv, bb);
            uint4 pk;
            pk.x = pack2(f2bf(bb[0]), f2bf(bb[1]));
            pk.y = pack2(f2bf(bb[2]), f2bf(bb[3]));
            pk.z = pack2(f2bf(bb[4]), f2bf(bb[5]));
            pk.w = pack2(f2bf(bb[6]), f2bf(bb[7]));
            *(uint4*)(out + H + (size_t)i * 8) = pk;
        }
    }
}

// ---- Layer 1: pure bf16 MFMA GEMM — byte-identical to R8/R9/R10 (VGPR 76, ~208us).
__global__ __launch_bounds__(256) void kan1_gemm(
    const unsigned short* __restrict__ F, const unsigned short* __restrict__ wp,
    unsigned short* __restrict__ l1)
{
    __shared__ __align__(16) unsigned short sA[128 * 64];
    __shared__ __align__(16) unsigned short sB[128 * 64];
    const int b = blockIdx.x;          // 0..767
    const int xcd = b & 7, s = b >> 3; // s in 0..95
    const int rowT = xcd * 16 + s / 6;
    const int colT = s % 6;
    const int rowBase = rowT * 128, colBase = colT * 128;

    const int t = threadIdx.x;
    const int lane = t & 63, wv = t >> 6;
    const int quad = lane >> 4, lm = lane & 15;
    const int wr = wv & 1, wc = wv >> 1;
    const int p7 = lm & 7;

    floatx4 acc[4][4] = {};
    int aoff[4], boff[4], goff[2];
#pragma unroll
    for (int im = 0; im < 4; ++im) aoff[im] = (wr * 64 + im * 16 + lm) * 64;
#pragma unroll
    for (int in_ = 0; in_ < 4; ++in_) boff[in_] = (wc * 64 + in_ * 16 + lm) * 64;
#pragma unroll
    for (int kk = 0; kk < 2; ++kk) goff[kk] = ((kk * 4 + quad) ^ p7) * 8;

    const int br_off = lane >> 3;   // row within 8-row segment
    const int bg_slot = lane & 7;   // lds granule slot

#pragma unroll 1
    for (int kc = 0; kc < NCHUNK; ++kc) {
#pragma unroll
        for (int p = 0; p < 4; ++p) {
            int sseg = wv * 4 + p;
            int r = sseg * 8 + br_off;
            int g = bg_slot ^ (r & 7);
            const unsigned short* ga = F  + (size_t)(rowBase + r) * KEXP + kc * 64 + g * 8;
            const unsigned short* gb = wp + (size_t)(colBase + r) * KEXP + kc * 64 + g * 8;
            __builtin_amdgcn_global_load_lds(
                (const __attribute__((address_space(1))) void*)ga,
                (__attribute__((address_space(3))) void*)(sA + sseg * 512), 16, 0, 0);
            __builtin_amdgcn_global_load_lds(
                (const __attribute__((address_space(1))) void*)gb,
                (__attribute__((address_space(3))) void*)(sB + sseg * 512), 16, 0, 0);
        }
        __syncthreads();
#pragma unroll
        for (int kk = 0; kk < 2; ++kk) {
            bhalf8 af[4], bf[4];
#pragma unroll
            for (int im = 0; im < 4; ++im) af[im] = *(const bhalf8*)&sA[aoff[im] + goff[kk]];
#pragma unroll
            for (int in_ = 0; in_ < 4; ++in_) bf[in_] = *(const bhalf8*)&sB[boff[in_] + goff[kk]];
#pragma unroll
            for (int im = 0; im < 4; ++im)
#pragma unroll
                for (int in_ = 0; in_ < 4; ++in_)
                    acc[im][in_] = __builtin_amdgcn_mfma_f32_16x16x32_bf16(
                        af[im], bf[in_], acc[im][in_], 0, 0, 0);
        }
        __syncthreads();
    }
#pragma unroll
    for (int im = 0; im < 4; ++im) {
#pragma unroll
        for (int in_ = 0; in_ < 4; ++in_) {
            int col = colBase + wc * 64 + in_ * 16 + lm;
            size_t rbase = (size_t)(rowBase + wr * 64 + im * 16 + quad * 4);
#pragma unroll
            for (int reg = 0; reg < 4; ++reg)
                l1[(rbase + reg) * H + col] = f2bf(acc[im][in_][reg]);
        }
    }
}

// ---- Layer 2 v4 (transposed): lane = channel, loop over rows.
// 768 threads = 12 waves cover all channels; weights live in REGISTERS
// (loaded once, scaler folded in fp32). Per row-step: one coalesced 128B
// l1 load per wave + ~70 VALU + 6-step butterfly; 12 partials/row combined
// via LDS. vmem instrs per element: 9 -> ~0.02.
__global__ __launch_bounds__(768) void kan2_kernel(
    const unsigned short* __restrict__ l1, const float* __restrict__ bw,
    const float* __restrict__ sw, const float* __restrict__ sc,
    float* __restrict__ out)
{
    __shared__ float sP[K2_BLK * 12 * 2];   // 6 KB
    const int t = threadIdx.x;
    const int w = t >> 6, lane = t & 63;
    const int c = t;                        // channel 0..767

    // per-channel weights, scaler folded (fp32 throughout)
    float s0 = sc[c], s1 = sc[H + c];
    float bw0 = bw[c], bw1 = bw[H + c];
    const float4* q0 = (const float4*)(sw + (size_t)c * 8);
    const float4* q1 = (const float4*)(sw + (size_t)(H + c) * 8);
    float4 wa = q0[0], wb = q0[1];
    float4 wcv = q1[0], wd = q1[1];
    float w0[8] = {wa.x*s0, wa.y*s0, wa.z*s0, wa.w*s0,
                   wb.x*s0, wb.y*s0, wb.z*s0, wb.w*s0};
    float w1[8] = {wcv.x*s1, wcv.y*s1, wcv.z*s1, wcv.w*s1,
                   wd.x*s1,  wd.y*s1,  wd.z*s1,  wd.w*s1};

    const int n0 = blockIdx.x * K2_BLK;
#pragma unroll 2
    for (int r = 0; r < K2_BLK; ++r) {
        int n = n0 + r;
        float h = bf2f(l1[(size_t)n * H + c]);
        float u = gelu_fast(h);
        float f0 = silu_f(u);
        float bb[8];
        kan_bases(u, bb);
        float v0 = f0 * bw0, v1 = f0 * bw1;
#pragma unroll
        for (int k = 0; k < 8; ++k) {
            v0 = fmaf(bb[k], w0[k], v0);
            v1 = fmaf(bb[k], w1[k], v1);
        }
#pragma unroll
        for (int off = 32; off > 0; off >>= 1) {
            v0 += __shfl_xor(v0, off, 64);
            v1 += __shfl_xor(v1, off, 64);
        }
        if (lane == 0) {
            sP[(r * 12 + w) * 2 + 0] = v0;
            sP[(r * 12 + w) * 2 + 1] = v1;
        }
    }
    __syncthreads();
    if (t < K2_BLK * 2) {
        int r = t >> 1, o = t & 1;
        float sum = 0.f;
#pragma unroll
        for (int k = 0; k < 12; ++k) sum += sP[(r * 12 + k) * 2 + o];
        out[(size_t)(n0 + r) * 2 + o] = sum;
    }
}

extern "C" void kernel_launch(void* const* d_in, const int* in_sizes, int n_in,
                              void* d_out, int out_size, void* d_ws, size_t ws_size,
                              hipStream_t stream) {
    const float* hidden = (const float*)d_in[0];
    const float* bw1    = (const float*)d_in[1];
    const float* sw1    = (const float*)d_in[2];
    const float* sc1    = (const float*)d_in[3];
    const float* bw2    = (const float*)d_in[4];
    const float* sw2    = (const float*)d_in[5];
    const float* sc2    = (const float*)d_in[6];
    float* out = (float*)d_out;

    // R4/R8/R9/R10 workspace layout exactly: l1, wp, F
    const size_t l1_elems = (size_t)NROWS * H;     // 25.2 MB bf16
    const size_t wp_elems = (size_t)H * KEXP;      // 10.6 MB bf16
    unsigned short* l1 = (unsigned short*)d_ws;
    unsigned short* wp = l1 + l1_elems;
    unsigned short* F  = wp + wp_elems;            // 226.5 MB bf16

    prep_expand<<<H + NROWS, 256, 0, stream>>>(hidden, bw1, sw1, sc1, wp, F);
    kan1_gemm<<<768, 256, 0, stream>>>(F, wp, l1);
    kan2_kernel<<<NROWS / K2_BLK, 768, 0, stream>>>(l1, bw2, sw2, sc2, out);
}